// Round 1
// baseline (221.231 us; speedup 1.0000x reference)
//
#include <hip/hip_runtime.h>
#include <hip/hip_bf16.h>

// AFT-Full: B=4, T=2048, DIM=1024, HID=256
// Pipeline (all bf16 MFMA GEMMs, f32 accumulate):
//   convert_x   : x f32 -> xb bf16 [8192][1024]
//   convert_ew  : ewb bf16 [2048][2048] = bf16(exp(wbias))
//   convert_w   : WqkvT bf16 [768][1024] (=W^T), WpT bf16 [1024][256], biascat f32[768]
//   gemm1       : C1 = xb @ WqkvT^T + biascat   -> QKV f32 [8192][768]
//   elt1        : B2T bf16 [2048][2048]: rows b*512+h = eK*V, b*512+256+h = eK (LDS-tiled transpose)
//   gemm2       : C2 = ewb @ B2T^T              -> f32 [2048][2048]  (num|den)
//   elt2        : Yt bf16 [8192][256] = sigmoid(Q) * num/den
//   gemm3       : out = Yt @ WpT^T + bp         -> f32 [8192][1024]
// Workspace layout (bytes): needs ~61 MB
//   [0,16M)        xb            (reused as C2 after gemm1)
//   [16M, +1.5M)   WqkvT
//   [18350080,+512K) WpT
//   [18874368,+3K) biascat
//   [18878464,+8M) ewb           (reused as Yt after gemm2)
//   [27267072,+24M) C1
//   [52432896,+8M) B2T

#define T_   2048
#define DIM_ 1024
#define HID_ 256
#define B_   4

typedef __attribute__((ext_vector_type(8))) short bf16x8;
typedef __attribute__((ext_vector_type(4))) float f32x4;

static __device__ __forceinline__ unsigned short f2b(float f) {
  __hip_bfloat16 h = __float2bfloat16(f);
  return __builtin_bit_cast(unsigned short, h);
}

static __device__ __forceinline__ void gld16(const void* g, const void* l) {
  __builtin_amdgcn_global_load_lds((const __attribute__((address_space(1))) void*)g,
                                   (__attribute__((address_space(3))) void*)l, 16, 0, 0);
}

// C[M][N] = A[M][K] * Bt[N][K]^T (+ bias[col]); all dims multiples of 128 (K mult of 32)
__global__ __launch_bounds__(256) void gemm_bt(
    const unsigned short* __restrict__ A,
    const unsigned short* __restrict__ Bt,
    float* __restrict__ C,
    const float* __restrict__ bias,
    int M, int N, int K)
{
  __shared__ unsigned short As[128 * 32];
  __shared__ unsigned short Bs[128 * 32];
  const int tid  = threadIdx.x;
  const int lane = tid & 63;
  const int wave = tid >> 6;
  const int wr = wave >> 1, wc = wave & 1;
  const long bm = (long)blockIdx.y * 128;
  const long bn = (long)blockIdx.x * 128;

  // staging map: flat 16B unit f = i*256 + tid ; row = f>>2 ; k elem = (f&3)*8
  const int srow = tid >> 2;
  const int sk   = (tid & 3) * 8;
  const unsigned short* ap0 = A  + (bm + srow)      * (long)K + sk;
  const unsigned short* ap1 = A  + (bm + srow + 64) * (long)K + sk;
  const unsigned short* bp0 = Bt + (bn + srow)      * (long)K + sk;
  const unsigned short* bp1 = Bt + (bn + srow + 64) * (long)K + sk;

  char* AsB = (char*)As;
  char* BsB = (char*)Bs;
  char* ldsA0 = AsB + wave * 1024;
  char* ldsA1 = AsB + 4096 + wave * 1024;
  char* ldsB0 = BsB + wave * 1024;
  char* ldsB1 = BsB + 4096 + wave * 1024;

  f32x4 acc[4][4] = {};

  const int fr  = lane & 15;          // fragment row/col within 16
  const int fkb = (lane >> 4) * 16;   // fragment k byte offset: (lane>>4)*8 elems * 2B

  const int nk = K >> 5;
  for (int kt = 0; kt < nk; ++kt) {
    gld16(ap0, ldsA0);
    gld16(ap1, ldsA1);
    gld16(bp0, ldsB0);
    gld16(bp1, ldsB1);
    ap0 += 32; ap1 += 32; bp0 += 32; bp1 += 32;
    asm volatile("s_waitcnt vmcnt(0)" ::: "memory");
    __syncthreads();

    bf16x8 av[4], bv[4];
#pragma unroll
    for (int m = 0; m < 4; ++m)
      av[m] = *(const bf16x8*)(AsB + (wr * 64 + m * 16 + fr) * 64 + fkb);
#pragma unroll
    for (int n = 0; n < 4; ++n)
      bv[n] = *(const bf16x8*)(BsB + (wc * 64 + n * 16 + fr) * 64 + fkb);
#pragma unroll
    for (int m = 0; m < 4; ++m)
#pragma unroll
      for (int n = 0; n < 4; ++n)
        acc[m][n] = __builtin_amdgcn_mfma_f32_16x16x32_bf16(av[m], bv[n], acc[m][n], 0, 0, 0);
    __syncthreads();
  }

  // C/D layout: col = lane&15, row = (lane>>4)*4 + reg
  const long crow0 = bm + wr * 64 + ((lane >> 4) << 2);
  const long ccol0 = bn + wc * 64 + fr;
#pragma unroll
  for (int n = 0; n < 4; ++n) {
    const long col = ccol0 + n * 16;
    const float bb = bias ? bias[col] : 0.f;
#pragma unroll
    for (int m = 0; m < 4; ++m) {
#pragma unroll
      for (int r = 0; r < 4; ++r) {
        C[(crow0 + m * 16 + r) * (long)N + col] = acc[m][n][r] + bb;
      }
    }
  }
}

__global__ void convert_f2b(const float4* __restrict__ in, ushort4* __restrict__ out,
                            int n4, int doExp) {
  int i = blockIdx.x * blockDim.x + threadIdx.x;
  if (i >= n4) return;
  float4 v = in[i];
  if (doExp) { v.x = __expf(v.x); v.y = __expf(v.y); v.z = __expf(v.z); v.w = __expf(v.w); }
  ushort4 o;
  o.x = f2b(v.x); o.y = f2b(v.y); o.z = f2b(v.z); o.w = f2b(v.w);
  out[i] = o;
}

__global__ void convert_w(const float* __restrict__ Wq, const float* __restrict__ Wk,
                          const float* __restrict__ Wv, const float* __restrict__ bq,
                          const float* __restrict__ bk, const float* __restrict__ bv,
                          const float* __restrict__ Wp,
                          unsigned short* __restrict__ WqkvT,
                          unsigned short* __restrict__ WpT,
                          float* __restrict__ biascat) {
  int idx = blockIdx.x * 256 + threadIdx.x;
  if (idx < 768 * 1024) {           // WqkvT[n][k] = W{q,k,v}[k][n%256]
    int n = idx >> 10, k = idx & 1023;
    const float* W = (n < 256) ? Wq : (n < 512) ? Wk : Wv;
    WqkvT[idx] = f2b(W[k * 256 + (n & 255)]);
  }
  if (idx < 1024 * 256) {           // WpT[d][h] = Wp[h][d]
    int d = idx >> 8, h = idx & 255;
    WpT[idx] = f2b(Wp[h * 1024 + d]);
  }
  if (idx < 768) {
    const float* bb = (idx < 256) ? bq : (idx < 512) ? bk : bv;
    biascat[idx] = bb[idx & 255];
  }
}

// B2T[b*512+h][s] = bf16(eK*V), B2T[b*512+256+h][s] = bf16(eK); LDS-tiled 64x64 transpose
__global__ void elt1_kernel(const float* __restrict__ C1, unsigned short* __restrict__ B2T) {
  __shared__ unsigned short ekT[64][65];
  __shared__ unsigned short ekvT[64][65];
  const int h0 = blockIdx.x * 64;
  const int s0 = blockIdx.y * 64;
  const int b  = blockIdx.z;
  const int t  = threadIdx.x;
#pragma unroll
  for (int i = 0; i < 16; ++i) {
    int idx = i * 256 + t;
    int si = idx >> 6, hi = idx & 63;
    const float* base = C1 + (long)(b * T_ + s0 + si) * 768;
    float k = base[256 + h0 + hi];
    float v = base[512 + h0 + hi];
    float ek = __expf(k);
    ekT[hi][si]  = f2b(ek);
    ekvT[hi][si] = f2b(ek * v);
  }
  __syncthreads();
#pragma unroll
  for (int i = 0; i < 16; ++i) {
    int idx = i * 256 + t;
    int hi = idx >> 6, si = idx & 63;
    B2T[(long)(b * 512 + h0 + hi) * 2048 + s0 + si]       = ekvT[hi][si];
    B2T[(long)(b * 512 + 256 + h0 + hi) * 2048 + s0 + si] = ekT[hi][si];
  }
}

// Yt[m][h] = bf16( sigmoid(Q[m][h]) * num/den ), m = b*T+t
__global__ void elt2_kernel(const float* __restrict__ C1, const float* __restrict__ C2,
                            unsigned short* __restrict__ Yt) {
  int idx = blockIdx.x * 256 + threadIdx.x;   // 8192*256 total
  int h = idx & 255, m = idx >> 8;
  int b = m >> 11, tt = m & 2047;
  float q   = C1[(long)m * 768 + h];
  float num = C2[(long)tt * 2048 + b * 512 + h];
  float den = C2[(long)tt * 2048 + b * 512 + 256 + h];
  float sig = 1.f / (1.f + __expf(-q));
  Yt[idx] = f2b(sig * num / den);
}

extern "C" void kernel_launch(void* const* d_in, const int* in_sizes, int n_in,
                              void* d_out, int out_size, void* d_ws, size_t ws_size,
                              hipStream_t stream) {
  const float* x     = (const float*)d_in[0];
  const float* Wq    = (const float*)d_in[1];
  const float* bq    = (const float*)d_in[2];
  const float* Wk    = (const float*)d_in[3];
  const float* bk    = (const float*)d_in[4];
  const float* Wv    = (const float*)d_in[5];
  const float* bv    = (const float*)d_in[6];
  const float* Wp    = (const float*)d_in[7];
  const float* bp    = (const float*)d_in[8];
  const float* wbias = (const float*)d_in[9];

  char* ws = (char*)d_ws;
  unsigned short* xb    = (unsigned short*)(ws + 0);          // 16 MB (reused as C2)
  float*          C2    = (float*)(ws + 0);
  unsigned short* WqkvT = (unsigned short*)(ws + 16777216);   // 1.5 MB
  unsigned short* WpT   = (unsigned short*)(ws + 18350080);   // 512 KB
  float*          biascat = (float*)(ws + 18874368);          // 3 KB
  unsigned short* ewb   = (unsigned short*)(ws + 18878464);   // 8 MB (reused as Yt)
  unsigned short* Yt    = (unsigned short*)(ws + 18878464);
  float*          C1    = (float*)(ws + 27267072);            // 24 MB
  unsigned short* B2T   = (unsigned short*)(ws + 52432896);   // 8 MB
  float*          out   = (float*)d_out;

  convert_f2b<<<8192, 256, 0, stream>>>((const float4*)x, (ushort4*)xb, 2097152, 0);
  convert_f2b<<<4096, 256, 0, stream>>>((const float4*)wbias, (ushort4*)ewb, 1048576, 1);
  convert_w<<<3072, 256, 0, stream>>>(Wq, Wk, Wv, bq, bk, bv, Wp, WqkvT, WpT, biascat);

  gemm_bt<<<dim3(6, 64), 256, 0, stream>>>(xb, WqkvT, C1, biascat, 8192, 768, 1024);
  elt1_kernel<<<dim3(4, 32, 4), 256, 0, stream>>>(C1, B2T);
  gemm_bt<<<dim3(16, 16), 256, 0, stream>>>(ewb, B2T, C2, nullptr, 2048, 2048, 2048);
  elt2_kernel<<<8192, 256, 0, stream>>>(C1, C2, Yt);
  gemm_bt<<<dim3(8, 64), 256, 0, stream>>>(Yt, WpT, out, bp, 8192, 1024, 256);
}

// Round 2
// 201.079 us; speedup vs baseline: 1.1002x; 1.1002x over previous
//
#include <hip/hip_runtime.h>
#include <hip/hip_bf16.h>

// AFT-Full: B=4, T=2048, DIM=1024, HID=256
// Pipeline (all bf16 MFMA GEMMs, f32 accumulate):
//   prep        : x f32 -> xb bf16; ewb = bf16(exp(wbias)); WqkvT/WpT transposed bf16; biascat
//   gemm1 <64>  : C1 = xb @ WqkvT^T + biascat   -> QKV f32 [8192][768]     (768 blocks, 3/CU)
//   elt1        : B2T bf16 [2048][2048]: rows b*512+h = eK*V, +256+h = eK  (LDS transpose)
//   gemm2 <128> : C2 = ewb @ B2T^T  split-K x2  -> f32 [2][2048][2048]     (512 blocks, 2/CU)
//   elt2        : Yt bf16 [8192][256] = sigmoid(Q) * (num0+num1)/(den0+den1)
//   gemm3 <64>  : out = Yt @ WpT^T + bp         -> f32 [8192][1024]        (1024 blocks, 4/CU)
// Workspace (split-K layout, needs 76021760 B; falls back to single-slice BN=64 gemm2 otherwise):
//   [0,32M)  C2 partials   (overlaps xb[0,16M) + WqkvT + biascat, all dead before gemm2)
//   [32M,40M) ewb          (reused as Yt after gemm2)
//   [40M,64M) C1
//   [64M,72M) B2T
//   [72M,+512K) WpT

#define T_   2048
#define DIM_ 1024
#define HID_ 256
#define B_   4

typedef __attribute__((ext_vector_type(8))) short bf16x8;
typedef __attribute__((ext_vector_type(4))) float f32x4;

static __device__ __forceinline__ unsigned short f2b(float f) {
  __hip_bfloat16 h = __float2bfloat16(f);
  return __builtin_bit_cast(unsigned short, h);
}

static __device__ __forceinline__ void gld16(const void* g, const void* l) {
  __builtin_amdgcn_global_load_lds((const __attribute__((address_space(1))) void*)g,
                                   (__attribute__((address_space(3))) void*)l, 16, 0, 0);
}

// C[M][N] = A[M][K_sub] * Bt[N][K_sub]^T (+ bias[col]); tile 128 x BN, BK=32.
// blockIdx.z = K-slice (slice s covers k in [s*Ksub, (s+1)*Ksub)), writes C + z*M*N.
template <int BN>
__global__ __launch_bounds__(256) void gemm_bt(
    const unsigned short* __restrict__ A,
    const unsigned short* __restrict__ Bt,
    float* __restrict__ C,
    const float* __restrict__ bias,
    int M, int N, int K, int Ksub)
{
  __shared__ unsigned short As[128 * 32];
  __shared__ unsigned short Bs[BN * 32];
  const int tid  = threadIdx.x;
  const int lane = tid & 63;
  const int wave = tid >> 6;
  const int wr = wave >> 1, wc = wave & 1;
  const long bm = (long)blockIdx.y * 128;
  const long bn = (long)blockIdx.x * BN;
  const long kbase = (long)blockIdx.z * Ksub;

  // staging map: flat 16B unit u = i*256 + tid ; row = u>>2 ; k elem = (u&3)*8
  const int srow = tid >> 2;
  const int sk   = (tid & 3) * 8;
  const unsigned short* ap0 = A  + (bm + srow) * (long)K + kbase + sk;
  const unsigned short* ap1 = ap0 + 64 * (long)K;
  const unsigned short* bp0 = Bt + (bn + srow) * (long)K + kbase + sk;
  const unsigned short* bp1 = bp0 + 64 * (long)K;   // only used when BN==128

  char* AsB = (char*)As;
  char* BsB = (char*)Bs;
  char* ldsA0 = AsB + wave * 1024;
  char* ldsA1 = AsB + 4096 + wave * 1024;
  char* ldsB0 = BsB + wave * 1024;
  char* ldsB1 = BsB + 4096 + wave * 1024;

  constexpr int NF = BN / 32;          // 16-col fragments per wave
  f32x4 acc[4][NF] = {};

  const int fr  = lane & 15;           // fragment row/col within 16
  const int fkb = (lane >> 4) * 16;    // fragment k byte offset

  const int nk = Ksub >> 5;
  for (int kt = 0; kt < nk; ++kt) {
    gld16(ap0, ldsA0);
    gld16(ap1, ldsA1);
    gld16(bp0, ldsB0);
    if constexpr (BN == 128) gld16(bp1, ldsB1);
    ap0 += 32; ap1 += 32; bp0 += 32;
    if constexpr (BN == 128) bp1 += 32;
    asm volatile("s_waitcnt vmcnt(0)" ::: "memory");
    __syncthreads();

    bf16x8 av[4], bv[NF];
#pragma unroll
    for (int m = 0; m < 4; ++m)
      av[m] = *(const bf16x8*)(AsB + (wr * 64 + m * 16 + fr) * 64 + fkb);
#pragma unroll
    for (int n = 0; n < NF; ++n)
      bv[n] = *(const bf16x8*)(BsB + (wc * (BN / 2) + n * 16 + fr) * 64 + fkb);
#pragma unroll
    for (int m = 0; m < 4; ++m)
#pragma unroll
      for (int n = 0; n < NF; ++n)
        acc[m][n] = __builtin_amdgcn_mfma_f32_16x16x32_bf16(av[m], bv[n], acc[m][n], 0, 0, 0);
    __syncthreads();
  }

  // C/D layout: col = lane&15, row = (lane>>4)*4 + reg
  float* Cz = C + (long)blockIdx.z * M * (long)N;
  const long crow0 = bm + wr * 64 + ((lane >> 4) << 2);
  const long ccol0 = bn + wc * (BN / 2) + fr;
#pragma unroll
  for (int n = 0; n < NF; ++n) {
    const long col = ccol0 + n * 16;
    const float bb = bias ? bias[col] : 0.f;
#pragma unroll
    for (int m = 0; m < 4; ++m) {
#pragma unroll
      for (int r = 0; r < 4; ++r) {
        Cz[(crow0 + m * 16 + r) * (long)N + col] = acc[m][n][r] + bb;
      }
    }
  }
}

// One merged prep kernel: blocks [0,8192) convert x; [8192,12288) exp(wbias);
// [12288,15360) weight transposes + bias concat.
__global__ void prep_kernel(const float* __restrict__ x, const float* __restrict__ wbias,
                            const float* __restrict__ Wq, const float* __restrict__ Wk,
                            const float* __restrict__ Wv, const float* __restrict__ bq,
                            const float* __restrict__ bk, const float* __restrict__ bv,
                            const float* __restrict__ Wp,
                            unsigned short* __restrict__ xb, unsigned short* __restrict__ ewb,
                            unsigned short* __restrict__ WqkvT, unsigned short* __restrict__ WpT,
                            float* __restrict__ biascat) {
  const int bid = blockIdx.x;
  const int t = threadIdx.x;
  if (bid < 8192) {
    int i = bid * 256 + t;                     // 2M float4s of x
    float4 v = ((const float4*)x)[i];
    ushort4 o; o.x = f2b(v.x); o.y = f2b(v.y); o.z = f2b(v.z); o.w = f2b(v.w);
    ((ushort4*)xb)[i] = o;
  } else if (bid < 12288) {
    int i = (bid - 8192) * 256 + t;            // 1M float4s of wbias
    float4 v = ((const float4*)wbias)[i];
    ushort4 o;
    o.x = f2b(__expf(v.x)); o.y = f2b(__expf(v.y));
    o.z = f2b(__expf(v.z)); o.w = f2b(__expf(v.w));
    ((ushort4*)ewb)[i] = o;
  } else {
    int idx = (bid - 12288) * 256 + t;
    if (idx < 768 * 1024) {                    // WqkvT[n][k] = W{q,k,v}[k][n&255]
      int n = idx >> 10, k = idx & 1023;
      const float* W = (n < 256) ? Wq : (n < 512) ? Wk : Wv;
      WqkvT[idx] = f2b(W[k * 256 + (n & 255)]);
    }
    if (idx < 1024 * 256) {                    // WpT[d][h] = Wp[h][d]
      int d = idx >> 8, h = idx & 255;
      WpT[idx] = f2b(Wp[h * 1024 + d]);
    }
    if (idx < 768) {
      const float* bb = (idx < 256) ? bq : (idx < 512) ? bk : bv;
      biascat[idx] = bb[idx & 255];
    }
  }
}

// B2T[b*512+h][s] = bf16(eK*V), B2T[b*512+256+h][s] = bf16(eK); LDS-tiled 64x64 transpose
__global__ void elt1_kernel(const float* __restrict__ C1, unsigned short* __restrict__ B2T) {
  __shared__ unsigned short ekT[64][65];
  __shared__ unsigned short ekvT[64][65];
  const int h0 = blockIdx.x * 64;
  const int s0 = blockIdx.y * 64;
  const int b  = blockIdx.z;
  const int t  = threadIdx.x;
#pragma unroll
  for (int i = 0; i < 16; ++i) {
    int idx = i * 256 + t;
    int si = idx >> 6, hi = idx & 63;
    const float* base = C1 + (long)(b * T_ + s0 + si) * 768;
    float k = base[256 + h0 + hi];
    float v = base[512 + h0 + hi];
    float ek = __expf(k);
    ekT[hi][si]  = f2b(ek);
    ekvT[hi][si] = f2b(ek * v);
  }
  __syncthreads();
#pragma unroll
  for (int i = 0; i < 16; ++i) {
    int idx = i * 256 + t;
    int hi = idx >> 6, si = idx & 63;
    B2T[(long)(b * 512 + h0 + hi) * 2048 + s0 + si]       = ekvT[hi][si];
    B2T[(long)(b * 512 + 256 + h0 + hi) * 2048 + s0 + si] = ekT[hi][si];
  }
}

// Yt[m][h] = bf16( sigmoid(Q[m][h]) * num/den ), m = b*T+t; sums nslices split-K partials
__global__ void elt2_kernel(const float* __restrict__ C1, const float* __restrict__ C2,
                            unsigned short* __restrict__ Yt, int nslices) {
  int idx = blockIdx.x * 256 + threadIdx.x;   // 8192*256 total
  int h = idx & 255, m = idx >> 8;
  int b = m >> 11, tt = m & 2047;
  long i_num = (long)tt * 2048 + b * 512 + h;
  long i_den = i_num + 256;
  float q   = C1[(long)m * 768 + h];
  float num = C2[i_num];
  float den = C2[i_den];
  if (nslices == 2) {
    num += C2[i_num + 4194304];
    den += C2[i_den + 4194304];
  }
  float sig = 1.f / (1.f + __expf(-q));
  Yt[idx] = f2b(sig * num / den);
}

extern "C" void kernel_launch(void* const* d_in, const int* in_sizes, int n_in,
                              void* d_out, int out_size, void* d_ws, size_t ws_size,
                              hipStream_t stream) {
  const float* x     = (const float*)d_in[0];
  const float* Wq    = (const float*)d_in[1];
  const float* bq    = (const float*)d_in[2];
  const float* Wk    = (const float*)d_in[3];
  const float* bk    = (const float*)d_in[4];
  const float* Wv    = (const float*)d_in[5];
  const float* bv    = (const float*)d_in[6];
  const float* Wp    = (const float*)d_in[7];
  const float* bp    = (const float*)d_in[8];
  const float* wbias = (const float*)d_in[9];

  char* ws = (char*)d_ws;
  const bool big = ws_size >= 76021760ull;   // split-K layout fits?

  unsigned short *xb, *WqkvT, *WpT, *ewb, *Yt, *B2T;
  float *C1, *C2, *biascat;
  if (big) {
    xb      = (unsigned short*)(ws + 0);            // 16 MB (dead before gemm2)
    WqkvT   = (unsigned short*)(ws + 16777216);     // 1.5 MB (dead before gemm2)
    biascat = (float*)(ws + 18350080);              // 3 KB (dead before gemm2)
    C2      = (float*)(ws + 0);                     // 32 MB (2 split-K partials)
    ewb     = (unsigned short*)(ws + 33554432);     // 8 MB (reused as Yt)
    Yt      = (unsigned short*)(ws + 33554432);
    C1      = (float*)(ws + 41943040);              // 24 MB
    B2T     = (unsigned short*)(ws + 67108864);     // 8 MB
    WpT     = (unsigned short*)(ws + 75497472);     // 512 KB  -> total 76021760
  } else {
    xb      = (unsigned short*)(ws + 0);            // 16 MB (reused as C2, 1 slice)
    C2      = (float*)(ws + 0);
    WqkvT   = (unsigned short*)(ws + 16777216);
    WpT     = (unsigned short*)(ws + 18350080);
    biascat = (float*)(ws + 18874368);
    ewb     = (unsigned short*)(ws + 18878464);     // reused as Yt
    Yt      = (unsigned short*)(ws + 18878464);
    C1      = (float*)(ws + 27267072);
    B2T     = (unsigned short*)(ws + 52432896);
  }
  float* out = (float*)d_out;

  prep_kernel<<<15360, 256, 0, stream>>>(x, wbias, Wq, Wk, Wv, bq, bk, bv, Wp,
                                         xb, ewb, WqkvT, WpT, biascat);

  gemm_bt<64><<<dim3(12, 64, 1), 256, 0, stream>>>(xb, WqkvT, C1, biascat, 8192, 768, 1024, 1024);
  elt1_kernel<<<dim3(4, 32, 4), 256, 0, stream>>>(C1, B2T);
  if (big) {
    gemm_bt<128><<<dim3(16, 16, 2), 256, 0, stream>>>(ewb, B2T, C2, nullptr, 2048, 2048, 2048, 1024);
  } else {
    gemm_bt<64><<<dim3(32, 16, 1), 256, 0, stream>>>(ewb, B2T, C2, nullptr, 2048, 2048, 2048, 2048);
  }
  elt2_kernel<<<8192, 256, 0, stream>>>(C1, C2, Yt, big ? 2 : 1);
  gemm_bt<64><<<dim3(16, 64, 1), 256, 0, stream>>>(Yt, WpT, out, bp, 8192, 1024, 256, 256);
}

// Round 3
// 199.796 us; speedup vs baseline: 1.1073x; 1.0064x over previous
//
#include <hip/hip_runtime.h>
#include <hip/hip_bf16.h>

// AFT-Full: B=4, T=2048, DIM=1024, HID=256
// Pipeline (bf16 MFMA, f32 accum; all GEMMs BM=128 BN=64 BK=32, double-buffered
// single-barrier K-loop = T3 minimal 2-phase recipe):
//   prep      : xb=bf16(x); ewb=bf16(exp(wbias)); WqkvT interleaved (cols: 0..255=Q,
//               256+2h=K_h, 257+2h=V_h); WpT; biascat interleaved
//   gemm1_qkv : [8192x768] = xb @ WqkvT^T + biascat. Epilogue:
//               Q-cols -> sgQ f32 = sigmoid(q);  KV-cols -> shfl-pair (K,V) ->
//               B2T bf16 rows b*512+2h = exp(K)*V (num), b*512+2h+1 = exp(K) (den)
//   gemm2_aft : [2048t x 2048n'] = ewb @ B2T^T, full K=2048. Epilogue: ratio =
//               num/den via shfl pair, LDS-transpose, Yt[m][h] = sgQ * ratio (bf16)
//   gemm3     : out = Yt @ WpT^T + bp  -> f32 [8192][1024]
// Workspace (48.3 MB, no aliasing):
//   xb 0..16M | ewb 16M..24M | WqkvT +1.5M | WpT +0.5M | biascat +4K
//   sgQ 27267072 (+8M) | B2T 35655680 (+8M) | Yt 44044288 (+4M)

typedef __attribute__((ext_vector_type(8))) short bf16x8;
typedef __attribute__((ext_vector_type(4))) float f32x4;

static __device__ __forceinline__ unsigned short f2b(float f) {
  __hip_bfloat16 h = __float2bfloat16(f);
  return __builtin_bit_cast(unsigned short, h);
}

static __device__ __forceinline__ void gld16(const void* g, const void* l) {
  __builtin_amdgcn_global_load_lds((const __attribute__((address_space(1))) void*)g,
                                   (__attribute__((address_space(3))) void*)l, 16, 0, 0);
}

// Double-buffered K-loop: tile BM=128 x BN=64, BK=32.
// AsB: 2 x 8KB buffers, BsB: 2 x 4KB buffers. acc[4][2] per 2x2-wave layout.
// A_blk/Bt_blk already offset to the block's first row; row stride = K elements.
static __device__ __forceinline__ void gemm_loop(
    const unsigned short* __restrict__ A_blk,
    const unsigned short* __restrict__ Bt_blk,
    int K, int nk, char* AsB, char* BsB, f32x4 acc[4][2],
    int tid, int wr, int wc, int fr, int fkb)
{
  const int srow = tid >> 2;
  const int sk   = (tid & 3) * 8;
  const unsigned short* ap0 = A_blk + (long)srow * K + sk;
  const unsigned short* ap1 = ap0 + 64 * (long)K;
  const unsigned short* bp0 = Bt_blk + (long)srow * K + sk;

  // prologue: stage tile 0 into buf 0
  gld16(ap0, AsB + tid * 16);
  gld16(ap1, AsB + 4096 + tid * 16);
  gld16(bp0, BsB + tid * 16);
  ap0 += 32; ap1 += 32; bp0 += 32;
  __syncthreads();                       // drains vmcnt, tile 0 ready

  int buf = 0;
  for (int kt = 0; kt < nk; ++kt) {
    if (kt + 1 < nk) {                   // issue next-tile loads (overlap w/ MFMA)
      char* nA = AsB + ((buf ^ 1) << 13) + tid * 16;
      char* nB = BsB + ((buf ^ 1) << 12) + tid * 16;
      gld16(ap0, nA);
      gld16(ap1, nA + 4096);
      gld16(bp0, nB);
      ap0 += 32; ap1 += 32; bp0 += 32;
    }
    const char* Ab = AsB + (buf << 13);
    const char* Bb = BsB + (buf << 12);
    bf16x8 av[4], bv[2];
#pragma unroll
    for (int m = 0; m < 4; ++m)
      av[m] = *(const bf16x8*)(Ab + (wr * 64 + m * 16 + fr) * 64 + fkb);
#pragma unroll
    for (int n = 0; n < 2; ++n)
      bv[n] = *(const bf16x8*)(Bb + (wc * 32 + n * 16 + fr) * 64 + fkb);
#pragma unroll
    for (int m = 0; m < 4; ++m)
#pragma unroll
      for (int n = 0; n < 2; ++n)
        acc[m][n] = __builtin_amdgcn_mfma_f32_16x16x32_bf16(av[m], bv[n], acc[m][n], 0, 0, 0);
    __syncthreads();                     // next tile staged + everyone done reading cur
    buf ^= 1;
  }
}

// ---------------- gemm1: QKV projection with fused exp/transpose epilogue -------
__global__ __launch_bounds__(256) void gemm1_qkv(
    const unsigned short* __restrict__ xb, const unsigned short* __restrict__ WqkvT,
    const float* __restrict__ biascat,
    float* __restrict__ sgQ, unsigned short* __restrict__ B2T)
{
  __shared__ char AsB[16384];
  __shared__ char BsB[8192];
  const int tid = threadIdx.x, lane = tid & 63, wave = tid >> 6;
  const int wr = wave >> 1, wc = wave & 1;
  const int fr = lane & 15, fkb = (lane >> 4) * 16, q4 = (lane >> 4) * 2 * 2;
  const long bm = (long)blockIdx.y * 128;   // row in [0,8192)
  const long bn = (long)blockIdx.x * 64;    // col in [0,768)
  const int  b  = (int)(bm >> 11);
  const int  tb = (int)(bm & 2047);

  f32x4 acc[4][2] = {};
  gemm_loop(xb + bm * 1024, WqkvT + bn * 1024, 1024, 32, AsB, BsB, acc,
            tid, wr, wc, fr, fkb);

  if (bn < 256) {
    // Q block: sigmoid -> sgQ f32 [8192][256]
#pragma unroll
    for (int n = 0; n < 2; ++n) {
      const int col = (int)bn + wc * 32 + n * 16 + fr;
      const float bb = biascat[col];
#pragma unroll
      for (int m = 0; m < 4; ++m) {
#pragma unroll
        for (int r = 0; r < 4; ++r) {
          long row = bm + wr * 64 + m * 16 + q4 + r;
          float v = acc[m][n][r] + bb;
          sgQ[row * 256 + col] = 1.f / (1.f + __expf(-v));
        }
      }
    }
  } else {
    // KV block: pair K (even u) with V (odd u) via shfl, write B2T interleaved
#pragma unroll
    for (int n = 0; n < 2; ++n) {
      const int col = (int)bn + wc * 32 + n * 16 + fr;
      const int u   = col - 256;
      const float bb = biascat[col];
      const bool isK = (u & 1) == 0;
      const long rw = (long)b * 512 + u + (isK ? 1 : -1);
#pragma unroll
      for (int m = 0; m < 4; ++m) {
        float v[4], o[4];
#pragma unroll
        for (int r = 0; r < 4; ++r) v[r] = acc[m][n][r] + bb;
#pragma unroll
        for (int r = 0; r < 4; ++r) o[r] = __shfl_xor(v[r], 1);
        ushort4 pk;
        if (isK) {       // store exp(K) to den row
          pk.x = f2b(__expf(v[0])); pk.y = f2b(__expf(v[1]));
          pk.z = f2b(__expf(v[2])); pk.w = f2b(__expf(v[3]));
        } else {         // store exp(K)*V to num row (K came from even neighbor)
          pk.x = f2b(__expf(o[0]) * v[0]); pk.y = f2b(__expf(o[1]) * v[1]);
          pk.z = f2b(__expf(o[2]) * v[2]); pk.w = f2b(__expf(o[3]) * v[3]);
        }
        const int t0 = tb + wr * 64 + m * 16 + q4;
        *(ushort4*)(B2T + rw * 2048 + t0) = pk;
      }
    }
  }
}

// ---------------- gemm2: AFT mixing with fused ratio/output epilogue ------------
__global__ __launch_bounds__(256) void gemm2_aft(
    const unsigned short* __restrict__ ewb, const unsigned short* __restrict__ B2T,
    const float* __restrict__ sgQ, unsigned short* __restrict__ Yt)
{
  __shared__ char AsB[16384];
  __shared__ char BsB[8192];
  __shared__ float epi[128 * 32];       // 16KB, used after loop
  const int tid = threadIdx.x, lane = tid & 63, wave = tid >> 6;
  const int wr = wave >> 1, wc = wave & 1;
  const int fr = lane & 15, fkb = (lane >> 4) * 16, q4 = (lane >> 4) * 2 * 2;
  const long bm = (long)blockIdx.y * 128;   // t-tile in [0,2048)
  const long bn = (long)blockIdx.x * 64;    // n'-tile in [0,2048)
  const int  b  = (int)(bn >> 9);
  const int  h0 = (int)((bn & 511) >> 1);   // 32-aligned

  f32x4 acc[4][2] = {};
  gemm_loop(ewb + bm * 2048, B2T + bn * 2048, 2048, 64, AsB, BsB, acc,
            tid, wr, wc, fr, fkb);

  // pair num (even col) / den (odd col); even lanes write ratio to LDS
  const bool even = (fr & 1) == 0;
#pragma unroll
  for (int n = 0; n < 2; ++n) {
    const int hl = wc * 16 + n * 8 + (fr >> 1);
#pragma unroll
    for (int m = 0; m < 4; ++m) {
#pragma unroll
      for (int r = 0; r < 4; ++r) {
        float own = acc[m][n][r];
        float oth = __shfl_xor(own, 1);
        if (even) {
          int tl = wr * 64 + m * 16 + q4 + r;
          epi[tl * 32 + hl] = own / oth;    // num/den
        }
      }
    }
  }
  __syncthreads();

  // coalesced: each pass handles 8 rows x 32 h
  const long mbase = (long)b * 2048 + bm;
#pragma unroll
  for (int p = 0; p < 16; ++p) {
    int row = p * 8 + (tid >> 5);
    int hl  = tid & 31;
    long mrow = mbase + row;
    int  hg   = h0 + hl;
    float v = epi[row * 32 + hl] * sgQ[mrow * 256 + hg];
    Yt[mrow * 256 + hg] = f2b(v);
  }
}

// ---------------- gemm3: generic C = A @ Bt^T + bias ---------------------------
__global__ __launch_bounds__(256) void gemm_bt(
    const unsigned short* __restrict__ A, const unsigned short* __restrict__ Bt,
    float* __restrict__ C, const float* __restrict__ bias, int M, int N, int K)
{
  __shared__ char AsB[16384];
  __shared__ char BsB[8192];
  const int tid = threadIdx.x, lane = tid & 63, wave = tid >> 6;
  const int wr = wave >> 1, wc = wave & 1;
  const int fr = lane & 15, fkb = (lane >> 4) * 16, q4 = (lane >> 4) * 2 * 2;
  const long bm = (long)blockIdx.y * 128;
  const long bn = (long)blockIdx.x * 64;

  f32x4 acc[4][2] = {};
  gemm_loop(A + bm * (long)K, Bt + bn * (long)K, K, K >> 5, AsB, BsB, acc,
            tid, wr, wc, fr, fkb);

  const long crow0 = bm + wr * 64 + q4;
  const long ccol0 = bn + wc * 32 + fr;
#pragma unroll
  for (int n = 0; n < 2; ++n) {
    const long col = ccol0 + n * 16;
    const float bb = bias ? bias[col] : 0.f;
#pragma unroll
    for (int m = 0; m < 4; ++m)
#pragma unroll
      for (int r = 0; r < 4; ++r)
        C[(crow0 + m * 16 + r) * (long)N + col] = acc[m][n][r] + bb;
  }
}

// ---------------- prep ----------------------------------------------------------
__global__ void prep_kernel(const float* __restrict__ x, const float* __restrict__ wbias,
                            const float* __restrict__ Wq, const float* __restrict__ Wk,
                            const float* __restrict__ Wv, const float* __restrict__ bq,
                            const float* __restrict__ bk, const float* __restrict__ bv,
                            const float* __restrict__ Wp,
                            unsigned short* __restrict__ xb, unsigned short* __restrict__ ewb,
                            unsigned short* __restrict__ WqkvT, unsigned short* __restrict__ WpT,
                            float* __restrict__ biascat) {
  const int bid = blockIdx.x;
  const int t = threadIdx.x;
  if (bid < 8192) {
    int i = bid * 256 + t;                     // 2M float4s of x
    float4 v = ((const float4*)x)[i];
    ushort4 o; o.x = f2b(v.x); o.y = f2b(v.y); o.z = f2b(v.z); o.w = f2b(v.w);
    ((ushort4*)xb)[i] = o;
  } else if (bid < 12288) {
    int i = (bid - 8192) * 256 + t;            // 1M float4s of wbias
    float4 v = ((const float4*)wbias)[i];
    ushort4 o;
    o.x = f2b(__expf(v.x)); o.y = f2b(__expf(v.y));
    o.z = f2b(__expf(v.z)); o.w = f2b(__expf(v.w));
    ((ushort4*)ewb)[i] = o;
  } else {
    int idx = (bid - 12288) * 256 + t;
    if (idx < 768 * 1024) {                    // interleaved: n'<256 Q; 256+2h K_h; 257+2h V_h
      int n = idx >> 10, k = idx & 1023;
      const float* W; int c;
      if (n < 256) { W = Wq; c = n; }
      else { int u = n - 256; c = u >> 1; W = (u & 1) ? Wv : Wk; }
      WqkvT[idx] = f2b(W[k * 256 + c]);
    }
    if (idx < 1024 * 256) {                    // WpT[d][h] = Wp[h][d]
      int d = idx >> 8, h = idx & 255;
      WpT[idx] = f2b(Wp[h * 1024 + d]);
    }
    if (idx < 768) {
      float v;
      if (idx < 256) v = bq[idx];
      else { int u = idx - 256; v = (u & 1) ? bv[u >> 1] : bk[u >> 1]; }
      biascat[idx] = v;
    }
  }
}

extern "C" void kernel_launch(void* const* d_in, const int* in_sizes, int n_in,
                              void* d_out, int out_size, void* d_ws, size_t ws_size,
                              hipStream_t stream) {
  const float* x     = (const float*)d_in[0];
  const float* Wq    = (const float*)d_in[1];
  const float* bq    = (const float*)d_in[2];
  const float* Wk    = (const float*)d_in[3];
  const float* bk    = (const float*)d_in[4];
  const float* Wv    = (const float*)d_in[5];
  const float* bv    = (const float*)d_in[6];
  const float* Wp    = (const float*)d_in[7];
  const float* bp    = (const float*)d_in[8];
  const float* wbias = (const float*)d_in[9];

  char* ws = (char*)d_ws;
  unsigned short* xb      = (unsigned short*)(ws + 0);         // 16 MB
  unsigned short* ewb     = (unsigned short*)(ws + 16777216);  // 8 MB
  unsigned short* WqkvT   = (unsigned short*)(ws + 25165824);  // 1.5 MB
  unsigned short* WpT     = (unsigned short*)(ws + 26738688);  // 512 KB
  float*          biascat = (float*)(ws + 27262976);           // 4 KB
  float*          sgQ     = (float*)(ws + 27267072);           // 8 MB
  unsigned short* B2T     = (unsigned short*)(ws + 35655680);  // 8 MB
  unsigned short* Yt      = (unsigned short*)(ws + 44044288);  // 4 MB
  float* out = (float*)d_out;

  prep_kernel<<<15360, 256, 0, stream>>>(x, wbias, Wq, Wk, Wv, bq, bk, bv, Wp,
                                         xb, ewb, WqkvT, WpT, biascat);
  gemm1_qkv<<<dim3(12, 64), 256, 0, stream>>>(xb, WqkvT, biascat, sgQ, B2T);
  gemm2_aft<<<dim3(32, 16), 256, 0, stream>>>(ewb, B2T, sgQ, Yt);
  gemm_bt<<<dim3(16, 64), 256, 0, stream>>>(Yt, WpT, out, bp, 8192, 1024, 256);
}